// Round 13
// baseline (216.585 us; speedup 1.0000x reference)
//
#include <hip/hip_runtime.h>
#include <math.h>

extern "C" __device__ float __ocml_native_exp2_f32(float);

namespace {

typedef __attribute__((ext_vector_type(8))) short short8;   // 8 bf16 = 4 VGPRs
typedef __attribute__((ext_vector_type(4))) short short4b;  // 4 bf16 = 8B store
typedef __attribute__((ext_vector_type(4))) float floatx4;  // MFMA C/D frag

constexpr int B_ = 2;
constexpr int S_ = 2048;
constexpr int DM_ = 1024;
constexpr int NH_ = 16;
constexpr int HD_ = 64;

// fp32 -> bf16 round-to-nearest-even
__device__ inline unsigned short f2bf(float f) {
  unsigned u = __builtin_bit_cast(unsigned, f);
  u += 0x7fffu + ((u >> 16) & 1u);
  return (unsigned short)(u >> 16);
}

// DPP row-rotate (within 16-lane rows) — reduction butterflies without LDS.
template <int CTRL>
__device__ inline float dpp_ror(float x) {
  const int r = __builtin_amdgcn_update_dpp(
      0, __builtin_bit_cast(int, x), CTRL, 0xF, 0xF, false);
  return __builtin_bit_cast(float, r);
}

// async global->LDS, 16B per lane; lds dest must be wave-uniform (lane i lands
// at lds + i*16).
__device__ inline void gl2lds16(const unsigned short* g, unsigned short* l) {
  __builtin_amdgcn_global_load_lds(
      (const __attribute__((address_space(1))) unsigned int*)g,
      (__attribute__((address_space(3))) unsigned int*)l, 16, 0, 0);
}

// ---------------------------------------------------------------------------
// Fused prep: one launch does all three f32->bf16 conversions (dsts are
// contiguous in workspace: hb | wqb | wob) + the 2 length reductions.
// ---------------------------------------------------------------------------
__global__ __launch_bounds__(256) void prep(
    const float* __restrict__ hidden, const float* __restrict__ wqkv,
    const float* __restrict__ wout, const unsigned char* __restrict__ mask,
    unsigned short* __restrict__ hb, int* __restrict__ lengths) {
  const int bid = blockIdx.x;
  if (bid < 4096) {
    const int i = bid * 256 + threadIdx.x;  // short8 index into combined dst
    const float* src;
    int off;
    if (i < 524288)              { src = hidden; off = 0; }
    else if (i < 524288 + 393216){ src = wqkv;   off = 524288; }
    else                         { src = wout;   off = 524288 + 393216; }
    const size_t j = (size_t)(i - off);
    const float4 a = ((const float4*)src)[j * 2];
    const float4 b = ((const float4*)src)[j * 2 + 1];
    short8 v;
    v[0] = (short)f2bf(a.x); v[1] = (short)f2bf(a.y);
    v[2] = (short)f2bf(a.z); v[3] = (short)f2bf(a.w);
    v[4] = (short)f2bf(b.x); v[5] = (short)f2bf(b.y);
    v[6] = (short)f2bf(b.z); v[7] = (short)f2bf(b.w);
    ((short8*)hb)[i] = v;
  } else {
    const int b = bid - 4096;
    const int es1 = (mask[1] != 0);  // byte-1 nonzero => 1-byte bool storage
    __shared__ int cnt;
    if (threadIdx.x == 0) cnt = 0;
    __syncthreads();
    int local = 0;
    for (int s = threadIdx.x; s < S_; s += blockDim.x) {
      bool nz;
      if (es1) nz = mask[b * S_ + s] != 0;
      else     nz = ((const unsigned int*)mask)[b * S_ + s] != 0;
      local += nz ? 1 : 0;
    }
    atomicAdd(&cnt, local);
    __syncthreads();
    if (threadIdx.x == 0) lengths[b] = cnt;
  }
}

// ---------------------------------------------------------------------------
// QKV GEMM (bf16 MFMA): C[m][n] = sum_k A[m][k] * W[n][k]
// M=4096, N=3072, K=1024.
// NEW: 128x64 tiles -> 1536 blocks = 6/CU resident (was 3/CU at 128x128) —
// doubles the co-resident compute available to hide each block's barrier
// vmcnt-drain (the binding constraint; same move fixed out_gemm in r11).
// LDS 24KB, acc 8 x floatx4 (32 VGPR). BK=64 as two BK=32 half-tiles.
// 4 waves each 64x32. XCD-chunked map: each XCD owns 8 m-groups x 24
// n-groups (A-panel 2MB + W-panel 3MB fits 4MB L2). Coalesced epilogues;
// q pre-scaled by 1/8*log2(e) for base-2 flash softmax.
// ---------------------------------------------------------------------------
__global__ __launch_bounds__(256) void qkv_gemm(
    const unsigned short* __restrict__ A, const unsigned short* __restrict__ W,
    const int* __restrict__ pos_xyz,
    unsigned short* __restrict__ Qb, unsigned short* __restrict__ Kb,
    unsigned short* __restrict__ Vtb) {
  __shared__ __align__(16) unsigned short As[2][128 * 32];
  __shared__ __align__(16) unsigned short Bs[2][64 * 32];
  // lin -> (xcd, t); xcd owns m-groups [ (xcd>>1)*8, +8 ) x n-groups
  // [ (xcd&1)*24, +24 ). Bijective since 1536 % 8 == 0.
  const int lin = blockIdx.x;                           // 0..1535
  const int xcd = lin & 7, t = lin >> 3;                // t 0..191
  const int m0 = ((xcd >> 1) * 8 + t / 24) * 128;       // 0..3968
  const int n0 = ((xcd & 1) * 24 + t % 24) * 64;        // 0..3008
  const int w = threadIdx.x >> 6, lane = threadIdx.x & 63;
  const int lm = lane & 15, q4 = lane >> 4;
  const int srowA = w * 32;                 // wave stages 32 rows of A
  const int srowB = w * 16;                 // and 16 rows of B
  const int r_in = lane >> 2, c_in = (lane & 3) * 8;
  const int wr = (w >> 1) * 64, wc = (w & 1) * 32;
  const int which = n0 >> 10;               // 0=Q 1=K 2=V (block-uniform)
  // acc: which==2 -> [mt(4)][nt(2)] at acc[mt*2+nt]; else [nt(2)][mt(4)]
  // at acc[nt*4+mt].
  floatx4 acc[8];
  const floatx4 z4 = {0.f, 0.f, 0.f, 0.f};
#pragma unroll
  for (int i = 0; i < 8; i++) acc[i] = z4;

  const unsigned short* gA0 = A + (size_t)(m0 + srowA + r_in) * DM_ + c_in;
  const unsigned short* gA1 = A + (size_t)(m0 + srowA + 16 + r_in) * DM_ + c_in;
  const unsigned short* gB0 = W + (size_t)(n0 + srowB + r_in) * DM_ + c_in;

  for (int k0 = 0; k0 < DM_; k0 += 64) {
#pragma unroll
    for (int hh = 0; hh < 2; hh++) {
      const int ko = k0 + hh * 32;
      gl2lds16(gA0 + ko, As[hh] + srowA * 32);
      gl2lds16(gA1 + ko, As[hh] + (srowA + 16) * 32);
      gl2lds16(gB0 + ko, Bs[hh] + srowB * 32);
    }
    __syncthreads();
#pragma unroll
    for (int hh = 0; hh < 2; hh++) {
      short8 af[4], bf[2];
#pragma unroll
      for (int t2 = 0; t2 < 4; t2++)
        af[t2] = *(const short8*)(As[hh] + (wr + t2 * 16 + lm) * 32 + q4 * 8);
#pragma unroll
      for (int t2 = 0; t2 < 2; t2++)
        bf[t2] = *(const short8*)(Bs[hh] + (wc + t2 * 16 + lm) * 32 + q4 * 8);
      if (which == 2) {
#pragma unroll
        for (int i = 0; i < 4; i++)
#pragma unroll
          for (int j = 0; j < 2; j++)
            acc[i * 2 + j] = __builtin_amdgcn_mfma_f32_16x16x32_bf16(
                af[i], bf[j], acc[i * 2 + j], 0, 0, 0);
      } else {
#pragma unroll
        for (int i = 0; i < 2; i++)
#pragma unroll
          for (int j = 0; j < 4; j++)
            acc[i * 4 + j] = __builtin_amdgcn_mfma_f32_16x16x32_bf16(
                bf[i], af[j], acc[i * 4 + j], 0, 0, 0);
      }
    }
    __syncthreads();
  }

  const int h = (n0 & 1023) >> 6;  // block covers 64 cols = one head-block
  if (which == 2) {
#pragma unroll
    for (int nt = 0; nt < 2; nt++) {
      const int d = wc + nt * 16 + lm;
#pragma unroll
      for (int mt = 0; mt < 4; mt++) {
        const int m = m0 + wr + mt * 16 + q4 * 4;
        const int bi = m >> 11, si = m & (S_ - 1);
        short4b pk;
#pragma unroll
        for (int r = 0; r < 4; r++) pk[r] = (short)f2bf(acc[mt * 2 + nt][r]);
        *(short4b*)(Vtb + ((size_t)(bi * NH_ + h) * HD_ + d) * S_ + si) = pk;
      }
    }
  } else {
    unsigned short* Dst = (which == 0) ? Qb : Kb;
    // q pre-scaled by 1/8 * log2(e) for base-2 flash softmax
    const float osc = (which == 0) ? 0.125f * 1.44269504088896f : 1.0f;
#pragma unroll
    for (int nt = 0; nt < 2; nt++) {
      const int dbase = wc + nt * 16 + q4 * 4;  // even; both pairs in-register
      const int p0 = dbase >> 1;           // even -> p0,p0+1 share an axis
      int axis, j0, dseg;
      if (p0 < 10)      { axis = 0; j0 = p0;      dseg = 20; }
      else if (p0 < 20) { axis = 1; j0 = p0 - 10; dseg = 20; }
      else              { axis = 2; j0 = p0 - 20; dseg = 24; }
      // 10000^(-2j/dseg) = exp(-2j/dseg * ln 1e4)
      const float invf0 =
          __expf(-(2.0f * (float)j0 / (float)dseg) * 9.210340371976184f);
      const float invf1 =
          __expf(-(2.0f * (float)(j0 + 1) / (float)dseg) * 9.210340371976184f);
#pragma unroll
      for (int mt = 0; mt < 4; mt++) {
        const int m = m0 + wr + mt * 16 + lm;
        const int bi = m >> 11, si = m & (S_ - 1);
        const int pos = pos_xyz[((size_t)bi * S_ + si) * 3 + axis];
        short4b pk;
#pragma unroll
        for (int u = 0; u < 2; u++) {
          const float ve = acc[nt * 4 + mt][2 * u];
          const float vo = acc[nt * 4 + mt][2 * u + 1];
          float sn, cs;
          sincosf((float)pos * (u ? invf1 : invf0), &sn, &cs);
          pk[2 * u]     = (short)f2bf(fmaf(ve, cs, -vo * sn) * osc);
          pk[2 * u + 1] = (short)f2bf(fmaf(vo, cs, ve * sn) * osc);
        }
        *(short4b*)(Dst + ((size_t)(bi * NH_ + h) * S_ + si) * HD_ + dbase) = pk;
      }
    }
  }
}

// ---------------------------------------------------------------------------
// Flash attention on MFMA (round-12 version, verified: common-path tile has
// zero cross-lane reductions; defer check on per-lane max; l as per-lane
// partial reduced once after the k-loop).
// ---------------------------------------------------------------------------
__global__ __launch_bounds__(256) void flash_mfma(
    const unsigned short* __restrict__ Q, const unsigned short* __restrict__ Kg,
    const unsigned short* __restrict__ Vt, const int* __restrict__ lengths,
    unsigned short* __restrict__ Oa) {
  __shared__ __align__(16) unsigned short Ks[2 * 64 * 64];
  __shared__ __align__(16) unsigned short Vs[2 * 64 * 64];
  __shared__ __align__(16) unsigned short Ps[4][16 * 64];

  const int lin = blockIdx.y * gridDim.x + blockIdx.x;  // 0..1023
  const int xcd = lin & 7, k = lin >> 3;                // k 0..127 within XCD
  const int s = k >> 5, c = k & 31;
  const int pc = (c & 1) ? 31 - (c >> 1) : (c >> 1);    // pair permutation
  const int qt = (s & 1) ? 31 - pc : pc;
  const int bh = xcd * 4 + s;                           // 4 bh per XCD (L2)
  const int b = bh >> 4, h = bh & 15;
  const int q0 = qt * 64;

  const int w = threadIdx.x >> 6, lane = threadIdx.x & 63;
  const int lm = lane & 15, q4 = lane >> 4;
  const int len = lengths[b];
  const unsigned short* Qp = Q + (size_t)bh * S_ * HD_;
  const unsigned short* Kp = Kg + (size_t)bh * S_ * HD_;
  const unsigned short* Vp = Vt + (size_t)bh * HD_ * S_;

  const int r8 = lane >> 3, c8 = lane & 7;
  const int rs0 = w * 16 + r8, rs1 = rs0 + 8;           // (rs1&7) == (rs0&7)
  const int cs = (c8 ^ (rs0 & 7)) << 3;                 // chunk -> shorts
  const unsigned short* gK0 = Kp + (size_t)rs0 * HD_ + cs;
  const unsigned short* gK1 = Kp + (size_t)rs1 * HD_ + cs;
  const unsigned short* gV0 = Vp + (size_t)rs0 * S_ + cs;
  const unsigned short* gV1 = Vp + (size_t)rs1 * S_ + cs;
  unsigned short* dK0 = Ks + w * 16 * 64;
  unsigned short* dK1 = Ks + (w * 16 + 8) * 64;
  unsigned short* dV0 = Vs + w * 16 * 64;
  unsigned short* dV1 = Vs + (w * 16 + 8) * 64;

  const int qrow = q0 + w * 16 + lm;  // A-operand row for this lane
  short8 qf[2];
  qf[0] = *(const short8*)(Qp + (size_t)qrow * HD_ + q4 * 8);
  qf[1] = *(const short8*)(Qp + (size_t)qrow * HD_ + 32 + q4 * 8);

  const floatx4 z4 = {0.f, 0.f, 0.f, 0.f};
  floatx4 o[4];
#pragma unroll
  for (int dt = 0; dt < 4; dt++) o[dt] = z4;
  float m_i[4], lp[4];  // m uniform per 16-lane group; lp per-lane partial
#pragma unroll
  for (int r = 0; r < 4; r++) { m_i[r] = -1e30f; lp[r] = 0.0f; }

  unsigned short* ps = Ps[w];
  const int ktiles = min(qt + 1, (len + 63) >> 6);

  // prologue: stage tile 0 into buffer 0
  gl2lds16(gK0, dK0);
  gl2lds16(gK1, dK1);
  gl2lds16(gV0, dV0);
  gl2lds16(gV1, dV1);
  __syncthreads();

  int cur = 0;
  for (int kt = 0; kt < ktiles; kt++) {
    const int k0 = kt * 64;
    if (kt + 1 < ktiles) {
      const size_t koff = (size_t)(k0 + 64) * HD_;
      const int nb = (cur ^ 1) * 4096;
      gl2lds16(gK0 + koff, dK0 + nb);
      gl2lds16(gK1 + koff, dK1 + nb);
      gl2lds16(gV0 + (k0 + 64), dV0 + nb);
      gl2lds16(gV1 + (k0 + 64), dV1 + nb);
    }
    const unsigned short* kc = Ks + cur * 4096;
    const unsigned short* vc = Vs + cur * 4096;

    // S = Q K^T  (64 cols in 4 n-tiles); K frags from swizzled LDS.
    floatx4 sc[4];
    __builtin_amdgcn_s_setprio(1);
#pragma unroll
    for (int nt = 0; nt < 4; nt++) {
      const int row = nt * 16 + lm, sw = row & 7;
      const unsigned short* kb = kc + row * 64;
      const short8 b0 = *(const short8*)(kb + ((q4 ^ sw) << 3));
      const short8 b1 = *(const short8*)(kb + (((q4 + 4) ^ sw) << 3));
      sc[nt] = __builtin_amdgcn_mfma_f32_16x16x32_bf16(qf[0], b0, z4, 0, 0, 0);
      sc[nt] = __builtin_amdgcn_mfma_f32_16x16x32_bf16(qf[1], b1, sc[nt], 0, 0, 0);
    }
    __builtin_amdgcn_s_setprio(0);
    // mask only where it can trigger: diagonal tile or len-tail tile
    if (kt == qt || k0 + 64 > len) {
#pragma unroll
      for (int nt = 0; nt < 4; nt++) {
        const int col = k0 + nt * 16 + lm;
#pragma unroll
        for (int r = 0; r < 4; r++) {
          const int row = q0 + w * 16 + q4 * 4 + r;
          if (col > row || col >= len) sc[nt][r] = -1e30f;
        }
      }
    }
    // online softmax, base-2. Common path: no cross-lane ops at all.
    float lmax[4];
#pragma unroll
    for (int r = 0; r < 4; r++)
      lmax[r] = fmaxf(fmaxf(sc[0][r], sc[1][r]), fmaxf(sc[2][r], sc[3][r]));
    const bool ok = (lmax[0] <= m_i[0] + 8.f) && (lmax[1] <= m_i[1] + 8.f) &&
                    (lmax[2] <= m_i[2] + 8.f) && (lmax[3] <= m_i[3] + 8.f);
    if (!__all(ok)) {
      // rare: full DPP row-max, update m (stays group-uniform), rescale o,lp
#pragma unroll
      for (int r = 0; r < 4; r++) {
        float mx = lmax[r];
        mx = fmaxf(mx, dpp_ror<0x121>(mx));
        mx = fmaxf(mx, dpp_ror<0x122>(mx));
        mx = fmaxf(mx, dpp_ror<0x124>(mx));
        mx = fmaxf(mx, dpp_ror<0x128>(mx));
        const float mt = fmaxf(m_i[r], mx);
        const float al = __ocml_native_exp2_f32(m_i[r] - mt);
        lp[r] *= al;
        m_i[r] = mt;
#pragma unroll
        for (int dt = 0; dt < 4; dt++) o[dt][r] *= al;
      }
    }
#pragma unroll
    for (int r = 0; r < 4; r++) {
      float rs = 0.0f;
#pragma unroll
      for (int nt = 0; nt < 4; nt++) {
        const float pp = __ocml_native_exp2_f32(sc[nt][r] - m_i[r]);
        sc[nt][r] = pp;
        rs += pp;
      }
      lp[r] += rs;  // per-lane partial; reduced once after the loop
    }
    // P: D-layout -> bf16 -> wave-private LDS strip, stride 64 + chunk-XOR
#pragma unroll
    for (int nt = 0; nt < 4; nt++)
#pragma unroll
      for (int r = 0; r < 4; r++) {
        const int row = q4 * 4 + r;
        const int cc = (((nt * 2 + (lm >> 3)) ^ (row & 7)) << 3) | (lm & 7);
        ps[row * 64 + cc] = f2bf(sc[nt][r]);
      }
    // O += P V   (V^T rows are d; V frags from swizzled LDS)
    __builtin_amdgcn_s_setprio(1);
#pragma unroll
    for (int ks = 0; ks < 2; ks++) {
      const short8 pf = *(const short8*)(
          ps + lm * 64 + ((((ks << 2) + q4) ^ (lm & 7)) << 3));
#pragma unroll
      for (int dt = 0; dt < 4; dt++) {
        const int row = dt * 16 + lm, sw = row & 7;
        const short8 vf = *(const short8*)(
            vc + row * 64 + ((((ks << 2) + q4) ^ sw) << 3));
        o[dt] = __builtin_amdgcn_mfma_f32_16x16x32_bf16(pf, vf, o[dt], 0, 0, 0);
      }
    }
    __builtin_amdgcn_s_setprio(0);
    __syncthreads();  // drains next-tile staging; all waves done reading cur
    cur ^= 1;
  }
  // one DPP sum-ladder per row to finish l, then normalize + write attn
  float invl[4];
#pragma unroll
  for (int r = 0; r < 4; r++) {
    float l = lp[r];
    l += dpp_ror<0x121>(l);
    l += dpp_ror<0x122>(l);
    l += dpp_ror<0x124>(l);
    l += dpp_ror<0x128>(l);
    invl[r] = 1.0f / l;
  }
#pragma unroll
  for (int dt = 0; dt < 4; dt++)
#pragma unroll
    for (int r = 0; r < 4; r++) {
      const int row = q0 + w * 16 + q4 * 4 + r;
      const int col = h * HD_ + dt * 16 + lm;
      Oa[((size_t)b * S_ + row) * DM_ + col] = f2bf(o[dt][r] * invl[r]);
    }
}

// ---------------------------------------------------------------------------
// Out projection (bf16 MFMA): C[m][n] = sum_k A[m][k] * W[n][k], fp32 out.
// M=4096, N=1024, K=1024. 64x64 tiles, 1024 blocks (4/CU), XCD-grouped.
// Swapped operands -> one float4 (16B) store per (nt,mt).
// (Round-11/12 version, verified.)
// ---------------------------------------------------------------------------
__global__ __launch_bounds__(256) void out_gemm(
    const unsigned short* __restrict__ A, const unsigned short* __restrict__ W,
    float* __restrict__ C) {
  __shared__ __align__(16) unsigned short As[64 * 32];
  __shared__ __align__(16) unsigned short Bs[64 * 32];
  const int lin = blockIdx.y * gridDim.x + blockIdx.x;  // 0..1023
  const int xcd = lin & 7, t = lin >> 3;                // t 0..127
  const int m0 = (xcd * 8 + (t >> 4)) * 64;             // 0..4095
  const int n0 = (t & 15) * 64;                         // 0..1023
  const int w = threadIdx.x >> 6, lane = threadIdx.x & 63;
  const int lm = lane & 15, q4 = lane >> 4;
  const int srow = w * 16;                  // wave stages 16 rows of A and B
  const int r_in = lane >> 2, c_in = (lane & 3) * 8;
  const int wr = (w >> 1) * 32, wc = (w & 1) * 32;
  floatx4 acc[2][2];  // acc[nt][mt]: row <-> n, col <-> m
  const floatx4 z4 = {0.f, 0.f, 0.f, 0.f};
#pragma unroll
  for (int i = 0; i < 2; i++)
#pragma unroll
    for (int j = 0; j < 2; j++) acc[i][j] = z4;

  for (int k0 = 0; k0 < DM_; k0 += 32) {
    gl2lds16(A + (size_t)(m0 + srow + r_in) * DM_ + k0 + c_in, As + srow * 32);
    gl2lds16(W + (size_t)(n0 + srow + r_in) * DM_ + k0 + c_in, Bs + srow * 32);
    __syncthreads();
    short8 af[2], bf[2];
#pragma unroll
    for (int t2 = 0; t2 < 2; t2++)
      af[t2] = *(const short8*)(As + (wr + t2 * 16 + lm) * 32 + q4 * 8);
#pragma unroll
    for (int t2 = 0; t2 < 2; t2++)
      bf[t2] = *(const short8*)(Bs + (wc + t2 * 16 + lm) * 32 + q4 * 8);
#pragma unroll
    for (int i = 0; i < 2; i++)
#pragma unroll
      for (int j = 0; j < 2; j++)
        acc[i][j] =
            __builtin_amdgcn_mfma_f32_16x16x32_bf16(bf[i], af[j], acc[i][j],
                                                    0, 0, 0);
    __syncthreads();
  }
#pragma unroll
  for (int nt = 0; nt < 2; nt++) {
    const int nbase = n0 + wc + nt * 16 + q4 * 4;
#pragma unroll
    for (int mt = 0; mt < 2; mt++) {
      const int m = m0 + wr + mt * 16 + lm;
      *(floatx4*)(C + (size_t)m * DM_ + nbase) = acc[nt][mt];
    }
  }
}

}  // namespace

extern "C" void kernel_launch(void* const* d_in, const int* in_sizes, int n_in,
                              void* d_out, int out_size, void* d_ws, size_t ws_size,
                              hipStream_t stream) {
  const float* hidden = (const float*)d_in[0];          // (2,2048,1024) f32
  const float* w_qkv = (const float*)d_in[1];           // (3072,1024) f32
  const float* w_out = (const float*)d_in[2];           // (1024,1024) f32
  const unsigned char* amask = (const unsigned char*)d_in[3];  // (2,2048) bool
  const int* pos_xyz = (const int*)d_in[5];             // (2,2048,3) i32
  float* out = (float*)d_out;                           // (2,2048,1024) f32

  constexpr size_t NHID = (size_t)B_ * S_ * DM_;        // 4,194,304
  constexpr size_t NWQ = (size_t)3 * DM_ * DM_;         // 3,145,728
  constexpr size_t NWO = (size_t)DM_ * DM_;             // 1,048,576
  constexpr size_t NQKV = (size_t)B_ * NH_ * S_ * HD_;  // 4,194,304

  unsigned short* hb = (unsigned short*)d_ws;
  unsigned short* wqb = hb + NHID;
  unsigned short* wob = wqb + NWQ;
  unsigned short* Qb = wob + NWO;
  unsigned short* Kb = Qb + NQKV;
  unsigned short* Vtb = Kb + NQKV;
  unsigned short* attn = Vtb + NQKV;
  int* lens = (int*)(attn + NQKV);

  prep<<<dim3(4096 + B_), dim3(256), 0, stream>>>(hidden, w_qkv, w_out, amask,
                                                  hb, lens);
  qkv_gemm<<<dim3(1536), dim3(256), 0, stream>>>(hb, wqb, pos_xyz, Qb, Kb,
                                                 Vtb);
  flash_mfma<<<dim3(S_ / 64, B_ * NH_), dim3(256), 0, stream>>>(
      Qb, Kb, Vtb, lens, attn);
  out_gemm<<<dim3(16, 64), dim3(256), 0, stream>>>(attn, wob, out);
}

// Round 14
// 209.881 us; speedup vs baseline: 1.0319x; 1.0319x over previous
//
#include <hip/hip_runtime.h>
#include <math.h>

extern "C" __device__ float __ocml_native_exp2_f32(float);

namespace {

typedef __attribute__((ext_vector_type(8))) short short8;   // 8 bf16 = 4 VGPRs
typedef __attribute__((ext_vector_type(4))) short short4b;  // 4 bf16 = 8B store
typedef __attribute__((ext_vector_type(4))) float floatx4;  // MFMA C/D frag

constexpr int B_ = 2;
constexpr int S_ = 2048;
constexpr int DM_ = 1024;
constexpr int NH_ = 16;
constexpr int HD_ = 64;

// fp32 -> bf16 round-to-nearest-even
__device__ inline unsigned short f2bf(float f) {
  unsigned u = __builtin_bit_cast(unsigned, f);
  u += 0x7fffu + ((u >> 16) & 1u);
  return (unsigned short)(u >> 16);
}

// DPP row-rotate (within 16-lane rows) — reduction butterflies without LDS.
template <int CTRL>
__device__ inline float dpp_ror(float x) {
  const int r = __builtin_amdgcn_update_dpp(
      0, __builtin_bit_cast(int, x), CTRL, 0xF, 0xF, false);
  return __builtin_bit_cast(float, r);
}

// async global->LDS, 16B per lane; lds dest must be wave-uniform (lane i lands
// at lds + i*16).
__device__ inline void gl2lds16(const unsigned short* g, unsigned short* l) {
  __builtin_amdgcn_global_load_lds(
      (const __attribute__((address_space(1))) unsigned int*)g,
      (__attribute__((address_space(3))) unsigned int*)l, 16, 0, 0);
}

// ---------------------------------------------------------------------------
// Fused prep: one launch does all three f32->bf16 conversions (dsts are
// contiguous in workspace: hb | wqb | wob) + the 2 length reductions.
// ---------------------------------------------------------------------------
__global__ __launch_bounds__(256) void prep(
    const float* __restrict__ hidden, const float* __restrict__ wqkv,
    const float* __restrict__ wout, const unsigned char* __restrict__ mask,
    unsigned short* __restrict__ hb, int* __restrict__ lengths) {
  const int bid = blockIdx.x;
  if (bid < 4096) {
    const int i = bid * 256 + threadIdx.x;  // short8 index into combined dst
    const float* src;
    int off;
    if (i < 524288)              { src = hidden; off = 0; }
    else if (i < 524288 + 393216){ src = wqkv;   off = 524288; }
    else                         { src = wout;   off = 524288 + 393216; }
    const size_t j = (size_t)(i - off);
    const float4 a = ((const float4*)src)[j * 2];
    const float4 b = ((const float4*)src)[j * 2 + 1];
    short8 v;
    v[0] = (short)f2bf(a.x); v[1] = (short)f2bf(a.y);
    v[2] = (short)f2bf(a.z); v[3] = (short)f2bf(a.w);
    v[4] = (short)f2bf(b.x); v[5] = (short)f2bf(b.y);
    v[6] = (short)f2bf(b.z); v[7] = (short)f2bf(b.w);
    ((short8*)hb)[i] = v;
  } else {
    const int b = bid - 4096;
    const int es1 = (mask[1] != 0);  // byte-1 nonzero => 1-byte bool storage
    __shared__ int cnt;
    if (threadIdx.x == 0) cnt = 0;
    __syncthreads();
    int local = 0;
    for (int s = threadIdx.x; s < S_; s += blockDim.x) {
      bool nz;
      if (es1) nz = mask[b * S_ + s] != 0;
      else     nz = ((const unsigned int*)mask)[b * S_ + s] != 0;
      local += nz ? 1 : 0;
    }
    atomicAdd(&cnt, local);
    __syncthreads();
    if (threadIdx.x == 0) lengths[b] = cnt;
  }
}

// ---------------------------------------------------------------------------
// QKV GEMM (bf16 MFMA): C[m][n] = sum_k A[m][k] * W[n][k]
// M=4096, N=3072, K=1024. 128x64 tiles -> 1536 blocks = 6/CU resident.
// BK=64 as two BK=32 half-tiles. 4 waves each 64x32. XCD-chunked map.
// Coalesced epilogues; q pre-scaled by 1/8*log2(e) for base-2 softmax.
// (Round-13 version, verified per-dispatch at 55.3 us.)
// ---------------------------------------------------------------------------
__global__ __launch_bounds__(256) void qkv_gemm(
    const unsigned short* __restrict__ A, const unsigned short* __restrict__ W,
    const int* __restrict__ pos_xyz,
    unsigned short* __restrict__ Qb, unsigned short* __restrict__ Kb,
    unsigned short* __restrict__ Vtb) {
  __shared__ __align__(16) unsigned short As[2][128 * 32];
  __shared__ __align__(16) unsigned short Bs[2][64 * 32];
  // lin -> (xcd, t); xcd owns m-groups [ (xcd>>1)*8, +8 ) x n-groups
  // [ (xcd&1)*24, +24 ). Bijective since 1536 % 8 == 0.
  const int lin = blockIdx.x;                           // 0..1535
  const int xcd = lin & 7, t = lin >> 3;                // t 0..191
  const int m0 = ((xcd >> 1) * 8 + t / 24) * 128;       // 0..3968
  const int n0 = ((xcd & 1) * 24 + t % 24) * 64;        // 0..3008
  const int w = threadIdx.x >> 6, lane = threadIdx.x & 63;
  const int lm = lane & 15, q4 = lane >> 4;
  const int srowA = w * 32;                 // wave stages 32 rows of A
  const int srowB = w * 16;                 // and 16 rows of B
  const int r_in = lane >> 2, c_in = (lane & 3) * 8;
  const int wr = (w >> 1) * 64, wc = (w & 1) * 32;
  const int which = n0 >> 10;               // 0=Q 1=K 2=V (block-uniform)
  // acc: which==2 -> [mt(4)][nt(2)] at acc[mt*2+nt]; else [nt(2)][mt(4)]
  // at acc[nt*4+mt].
  floatx4 acc[8];
  const floatx4 z4 = {0.f, 0.f, 0.f, 0.f};
#pragma unroll
  for (int i = 0; i < 8; i++) acc[i] = z4;

  const unsigned short* gA0 = A + (size_t)(m0 + srowA + r_in) * DM_ + c_in;
  const unsigned short* gA1 = A + (size_t)(m0 + srowA + 16 + r_in) * DM_ + c_in;
  const unsigned short* gB0 = W + (size_t)(n0 + srowB + r_in) * DM_ + c_in;

  for (int k0 = 0; k0 < DM_; k0 += 64) {
#pragma unroll
    for (int hh = 0; hh < 2; hh++) {
      const int ko = k0 + hh * 32;
      gl2lds16(gA0 + ko, As[hh] + srowA * 32);
      gl2lds16(gA1 + ko, As[hh] + (srowA + 16) * 32);
      gl2lds16(gB0 + ko, Bs[hh] + srowB * 32);
    }
    __syncthreads();
#pragma unroll
    for (int hh = 0; hh < 2; hh++) {
      short8 af[4], bf[2];
#pragma unroll
      for (int t2 = 0; t2 < 4; t2++)
        af[t2] = *(const short8*)(As[hh] + (wr + t2 * 16 + lm) * 32 + q4 * 8);
#pragma unroll
      for (int t2 = 0; t2 < 2; t2++)
        bf[t2] = *(const short8*)(Bs[hh] + (wc + t2 * 16 + lm) * 32 + q4 * 8);
      if (which == 2) {
#pragma unroll
        for (int i = 0; i < 4; i++)
#pragma unroll
          for (int j = 0; j < 2; j++)
            acc[i * 2 + j] = __builtin_amdgcn_mfma_f32_16x16x32_bf16(
                af[i], bf[j], acc[i * 2 + j], 0, 0, 0);
      } else {
#pragma unroll
        for (int i = 0; i < 2; i++)
#pragma unroll
          for (int j = 0; j < 4; j++)
            acc[i * 4 + j] = __builtin_amdgcn_mfma_f32_16x16x32_bf16(
                bf[i], af[j], acc[i * 4 + j], 0, 0, 0);
      }
    }
    __syncthreads();
  }

  const int h = (n0 & 1023) >> 6;  // block covers 64 cols = one head-block
  if (which == 2) {
#pragma unroll
    for (int nt = 0; nt < 2; nt++) {
      const int d = wc + nt * 16 + lm;
#pragma unroll
      for (int mt = 0; mt < 4; mt++) {
        const int m = m0 + wr + mt * 16 + q4 * 4;
        const int bi = m >> 11, si = m & (S_ - 1);
        short4b pk;
#pragma unroll
        for (int r = 0; r < 4; r++) pk[r] = (short)f2bf(acc[mt * 2 + nt][r]);
        *(short4b*)(Vtb + ((size_t)(bi * NH_ + h) * HD_ + d) * S_ + si) = pk;
      }
    }
  } else {
    unsigned short* Dst = (which == 0) ? Qb : Kb;
    // q pre-scaled by 1/8 * log2(e) for base-2 flash softmax
    const float osc = (which == 0) ? 0.125f * 1.44269504088896f : 1.0f;
#pragma unroll
    for (int nt = 0; nt < 2; nt++) {
      const int dbase = wc + nt * 16 + q4 * 4;  // even; both pairs in-register
      const int p0 = dbase >> 1;           // even -> p0,p0+1 share an axis
      int axis, j0, dseg;
      if (p0 < 10)      { axis = 0; j0 = p0;      dseg = 20; }
      else if (p0 < 20) { axis = 1; j0 = p0 - 10; dseg = 20; }
      else              { axis = 2; j0 = p0 - 20; dseg = 24; }
      // 10000^(-2j/dseg) = exp(-2j/dseg * ln 1e4)
      const float invf0 =
          __expf(-(2.0f * (float)j0 / (float)dseg) * 9.210340371976184f);
      const float invf1 =
          __expf(-(2.0f * (float)(j0 + 1) / (float)dseg) * 9.210340371976184f);
#pragma unroll
      for (int mt = 0; mt < 4; mt++) {
        const int m = m0 + wr + mt * 16 + lm;
        const int bi = m >> 11, si = m & (S_ - 1);
        const int pos = pos_xyz[((size_t)bi * S_ + si) * 3 + axis];
        short4b pk;
#pragma unroll
        for (int u = 0; u < 2; u++) {
          const float ve = acc[nt * 4 + mt][2 * u];
          const float vo = acc[nt * 4 + mt][2 * u + 1];
          float sn, cs;
          sincosf((float)pos * (u ? invf1 : invf0), &sn, &cs);
          pk[2 * u]     = (short)f2bf(fmaf(ve, cs, -vo * sn) * osc);
          pk[2 * u + 1] = (short)f2bf(fmaf(vo, cs, ve * sn) * osc);
        }
        *(short4b*)(Dst + ((size_t)(bi * NH_ + h) * S_ + si) * HD_ + dbase) = pk;
      }
    }
  }
}

// ---------------------------------------------------------------------------
// Flash attention on MFMA (round-12 version, verified: common-path tile has
// zero cross-lane reductions; defer check on per-lane max; l as per-lane
// partial reduced once after the k-loop).
// ---------------------------------------------------------------------------
__global__ __launch_bounds__(256) void flash_mfma(
    const unsigned short* __restrict__ Q, const unsigned short* __restrict__ Kg,
    const unsigned short* __restrict__ Vt, const int* __restrict__ lengths,
    unsigned short* __restrict__ Oa) {
  __shared__ __align__(16) unsigned short Ks[2 * 64 * 64];
  __shared__ __align__(16) unsigned short Vs[2 * 64 * 64];
  __shared__ __align__(16) unsigned short Ps[4][16 * 64];

  const int lin = blockIdx.y * gridDim.x + blockIdx.x;  // 0..1023
  const int xcd = lin & 7, k = lin >> 3;                // k 0..127 within XCD
  const int s = k >> 5, c = k & 31;
  const int pc = (c & 1) ? 31 - (c >> 1) : (c >> 1);    // pair permutation
  const int qt = (s & 1) ? 31 - pc : pc;
  const int bh = xcd * 4 + s;                           // 4 bh per XCD (L2)
  const int b = bh >> 4, h = bh & 15;
  const int q0 = qt * 64;

  const int w = threadIdx.x >> 6, lane = threadIdx.x & 63;
  const int lm = lane & 15, q4 = lane >> 4;
  const int len = lengths[b];
  const unsigned short* Qp = Q + (size_t)bh * S_ * HD_;
  const unsigned short* Kp = Kg + (size_t)bh * S_ * HD_;
  const unsigned short* Vp = Vt + (size_t)bh * HD_ * S_;

  const int r8 = lane >> 3, c8 = lane & 7;
  const int rs0 = w * 16 + r8, rs1 = rs0 + 8;           // (rs1&7) == (rs0&7)
  const int cs = (c8 ^ (rs0 & 7)) << 3;                 // chunk -> shorts
  const unsigned short* gK0 = Kp + (size_t)rs0 * HD_ + cs;
  const unsigned short* gK1 = Kp + (size_t)rs1 * HD_ + cs;
  const unsigned short* gV0 = Vp + (size_t)rs0 * S_ + cs;
  const unsigned short* gV1 = Vp + (size_t)rs1 * S_ + cs;
  unsigned short* dK0 = Ks + w * 16 * 64;
  unsigned short* dK1 = Ks + (w * 16 + 8) * 64;
  unsigned short* dV0 = Vs + w * 16 * 64;
  unsigned short* dV1 = Vs + (w * 16 + 8) * 64;

  const int qrow = q0 + w * 16 + lm;  // A-operand row for this lane
  short8 qf[2];
  qf[0] = *(const short8*)(Qp + (size_t)qrow * HD_ + q4 * 8);
  qf[1] = *(const short8*)(Qp + (size_t)qrow * HD_ + 32 + q4 * 8);

  const floatx4 z4 = {0.f, 0.f, 0.f, 0.f};
  floatx4 o[4];
#pragma unroll
  for (int dt = 0; dt < 4; dt++) o[dt] = z4;
  float m_i[4], lp[4];  // m uniform per 16-lane group; lp per-lane partial
#pragma unroll
  for (int r = 0; r < 4; r++) { m_i[r] = -1e30f; lp[r] = 0.0f; }

  unsigned short* ps = Ps[w];
  const int ktiles = min(qt + 1, (len + 63) >> 6);

  // prologue: stage tile 0 into buffer 0
  gl2lds16(gK0, dK0);
  gl2lds16(gK1, dK1);
  gl2lds16(gV0, dV0);
  gl2lds16(gV1, dV1);
  __syncthreads();

  int cur = 0;
  for (int kt = 0; kt < ktiles; kt++) {
    const int k0 = kt * 64;
    if (kt + 1 < ktiles) {
      const size_t koff = (size_t)(k0 + 64) * HD_;
      const int nb = (cur ^ 1) * 4096;
      gl2lds16(gK0 + koff, dK0 + nb);
      gl2lds16(gK1 + koff, dK1 + nb);
      gl2lds16(gV0 + (k0 + 64), dV0 + nb);
      gl2lds16(gV1 + (k0 + 64), dV1 + nb);
    }
    const unsigned short* kc = Ks + cur * 4096;
    const unsigned short* vc = Vs + cur * 4096;

    // S = Q K^T  (64 cols in 4 n-tiles); K frags from swizzled LDS.
    floatx4 sc[4];
    __builtin_amdgcn_s_setprio(1);
#pragma unroll
    for (int nt = 0; nt < 4; nt++) {
      const int row = nt * 16 + lm, sw = row & 7;
      const unsigned short* kb = kc + row * 64;
      const short8 b0 = *(const short8*)(kb + ((q4 ^ sw) << 3));
      const short8 b1 = *(const short8*)(kb + (((q4 + 4) ^ sw) << 3));
      sc[nt] = __builtin_amdgcn_mfma_f32_16x16x32_bf16(qf[0], b0, z4, 0, 0, 0);
      sc[nt] = __builtin_amdgcn_mfma_f32_16x16x32_bf16(qf[1], b1, sc[nt], 0, 0, 0);
    }
    __builtin_amdgcn_s_setprio(0);
    // mask only where it can trigger: diagonal tile or len-tail tile
    if (kt == qt || k0 + 64 > len) {
#pragma unroll
      for (int nt = 0; nt < 4; nt++) {
        const int col = k0 + nt * 16 + lm;
#pragma unroll
        for (int r = 0; r < 4; r++) {
          const int row = q0 + w * 16 + q4 * 4 + r;
          if (col > row || col >= len) sc[nt][r] = -1e30f;
        }
      }
    }
    // online softmax, base-2. Common path: no cross-lane ops at all.
    float lmax[4];
#pragma unroll
    for (int r = 0; r < 4; r++)
      lmax[r] = fmaxf(fmaxf(sc[0][r], sc[1][r]), fmaxf(sc[2][r], sc[3][r]));
    const bool ok = (lmax[0] <= m_i[0] + 8.f) && (lmax[1] <= m_i[1] + 8.f) &&
                    (lmax[2] <= m_i[2] + 8.f) && (lmax[3] <= m_i[3] + 8.f);
    if (!__all(ok)) {
      // rare: full DPP row-max, update m (stays group-uniform), rescale o,lp
#pragma unroll
      for (int r = 0; r < 4; r++) {
        float mx = lmax[r];
        mx = fmaxf(mx, dpp_ror<0x121>(mx));
        mx = fmaxf(mx, dpp_ror<0x122>(mx));
        mx = fmaxf(mx, dpp_ror<0x124>(mx));
        mx = fmaxf(mx, dpp_ror<0x128>(mx));
        const float mt = fmaxf(m_i[r], mx);
        const float al = __ocml_native_exp2_f32(m_i[r] - mt);
        lp[r] *= al;
        m_i[r] = mt;
#pragma unroll
        for (int dt = 0; dt < 4; dt++) o[dt][r] *= al;
      }
    }
#pragma unroll
    for (int r = 0; r < 4; r++) {
      float rs = 0.0f;
#pragma unroll
      for (int nt = 0; nt < 4; nt++) {
        const float pp = __ocml_native_exp2_f32(sc[nt][r] - m_i[r]);
        sc[nt][r] = pp;
        rs += pp;
      }
      lp[r] += rs;  // per-lane partial; reduced once after the loop
    }
    // P: D-layout -> bf16 -> wave-private LDS strip, stride 64 + chunk-XOR
#pragma unroll
    for (int nt = 0; nt < 4; nt++)
#pragma unroll
      for (int r = 0; r < 4; r++) {
        const int row = q4 * 4 + r;
        const int cc = (((nt * 2 + (lm >> 3)) ^ (row & 7)) << 3) | (lm & 7);
        ps[row * 64 + cc] = f2bf(sc[nt][r]);
      }
    // O += P V   (V^T rows are d; V frags from swizzled LDS)
    __builtin_amdgcn_s_setprio(1);
#pragma unroll
    for (int ks = 0; ks < 2; ks++) {
      const short8 pf = *(const short8*)(
          ps + lm * 64 + ((((ks << 2) + q4) ^ (lm & 7)) << 3));
#pragma unroll
      for (int dt = 0; dt < 4; dt++) {
        const int row = dt * 16 + lm, sw = row & 7;
        const short8 vf = *(const short8*)(
            vc + row * 64 + ((((ks << 2) + q4) ^ sw) << 3));
        o[dt] = __builtin_amdgcn_mfma_f32_16x16x32_bf16(pf, vf, o[dt], 0, 0, 0);
      }
    }
    __builtin_amdgcn_s_setprio(0);
    __syncthreads();  // drains next-tile staging; all waves done reading cur
    cur ^= 1;
  }
  // one DPP sum-ladder per row to finish l, then normalize + write attn
  float invl[4];
#pragma unroll
  for (int r = 0; r < 4; r++) {
    float l = lp[r];
    l += dpp_ror<0x121>(l);
    l += dpp_ror<0x122>(l);
    l += dpp_ror<0x124>(l);
    l += dpp_ror<0x128>(l);
    invl[r] = 1.0f / l;
  }
#pragma unroll
  for (int dt = 0; dt < 4; dt++)
#pragma unroll
    for (int r = 0; r < 4; r++) {
      const int row = q0 + w * 16 + q4 * 4 + r;
      const int col = h * HD_ + dt * 16 + lm;
      Oa[((size_t)b * S_ + row) * DM_ + col] = f2bf(o[dt][r] * invl[r]);
    }
}

// ---------------------------------------------------------------------------
// Out projection (bf16 MFMA): C[m][n] = sum_k A[m][k] * W[n][k], fp32 out.
// M=4096, N=1024, K=1024. 64x64 tiles, 1024 blocks (4/CU), XCD-grouped.
// NEW: BK=64 as two BK=32 half-tiles -> 16 K-iterations instead of 32 =
// half the barrier vmcnt-drain stalls, 16 MFMA per iteration (the same
// transform that helped qkv in r11). LDS 32KB (cap 5/CU >= 4 resident).
// Swapped operands -> one float4 (16B) store per (nt,mt).
// ---------------------------------------------------------------------------
__global__ __launch_bounds__(256) void out_gemm(
    const unsigned short* __restrict__ A, const unsigned short* __restrict__ W,
    float* __restrict__ C) {
  __shared__ __align__(16) unsigned short As[2][64 * 32];
  __shared__ __align__(16) unsigned short Bs[2][64 * 32];
  const int lin = blockIdx.y * gridDim.x + blockIdx.x;  // 0..1023
  const int xcd = lin & 7, t = lin >> 3;                // t 0..127
  const int m0 = (xcd * 8 + (t >> 4)) * 64;             // 0..4095
  const int n0 = (t & 15) * 64;                         // 0..1023
  const int w = threadIdx.x >> 6, lane = threadIdx.x & 63;
  const int lm = lane & 15, q4 = lane >> 4;
  const int srow = w * 16;                  // wave stages 16 rows of A and B
  const int r_in = lane >> 2, c_in = (lane & 3) * 8;
  const int wr = (w >> 1) * 32, wc = (w & 1) * 32;
  floatx4 acc[2][2];  // acc[nt][mt]: row <-> n, col <-> m
  const floatx4 z4 = {0.f, 0.f, 0.f, 0.f};
#pragma unroll
  for (int i = 0; i < 2; i++)
#pragma unroll
    for (int j = 0; j < 2; j++) acc[i][j] = z4;

  const unsigned short* gA0 = A + (size_t)(m0 + srow + r_in) * DM_ + c_in;
  const unsigned short* gB0 = W + (size_t)(n0 + srow + r_in) * DM_ + c_in;

  for (int k0 = 0; k0 < DM_; k0 += 64) {
#pragma unroll
    for (int hh = 0; hh < 2; hh++) {
      const int ko = k0 + hh * 32;
      gl2lds16(gA0 + ko, As[hh] + srow * 32);
      gl2lds16(gB0 + ko, Bs[hh] + srow * 32);
    }
    __syncthreads();
#pragma unroll
    for (int hh = 0; hh < 2; hh++) {
      short8 af[2], bf[2];
#pragma unroll
      for (int t2 = 0; t2 < 2; t2++)
        af[t2] = *(const short8*)(As[hh] + (wr + t2 * 16 + lm) * 32 + q4 * 8);
#pragma unroll
      for (int t2 = 0; t2 < 2; t2++)
        bf[t2] = *(const short8*)(Bs[hh] + (wc + t2 * 16 + lm) * 32 + q4 * 8);
#pragma unroll
      for (int i = 0; i < 2; i++)
#pragma unroll
        for (int j = 0; j < 2; j++)
          acc[i][j] = __builtin_amdgcn_mfma_f32_16x16x32_bf16(
              bf[i], af[j], acc[i][j], 0, 0, 0);
    }
    __syncthreads();
  }
#pragma unroll
  for (int nt = 0; nt < 2; nt++) {
    const int nbase = n0 + wc + nt * 16 + q4 * 4;
#pragma unroll
    for (int mt = 0; mt < 2; mt++) {
      const int m = m0 + wr + mt * 16 + lm;
      *(floatx4*)(C + (size_t)m * DM_ + nbase) = acc[nt][mt];
    }
  }
}

}  // namespace

extern "C" void kernel_launch(void* const* d_in, const int* in_sizes, int n_in,
                              void* d_out, int out_size, void* d_ws, size_t ws_size,
                              hipStream_t stream) {
  const float* hidden = (const float*)d_in[0];          // (2,2048,1024) f32
  const float* w_qkv = (const float*)d_in[1];           // (3072,1024) f32
  const float* w_out = (const float*)d_in[2];           // (1024,1024) f32
  const unsigned char* amask = (const unsigned char*)d_in[3];  // (2,2048) bool
  const int* pos_xyz = (const int*)d_in[5];             // (2,2048,3) i32
  float* out = (float*)d_out;                           // (2,2048,1024) f32

  constexpr size_t NHID = (size_t)B_ * S_ * DM_;        // 4,194,304
  constexpr size_t NWQ = (size_t)3 * DM_ * DM_;         // 3,145,728
  constexpr size_t NWO = (size_t)DM_ * DM_;             // 1,048,576
  constexpr size_t NQKV = (size_t)B_ * NH_ * S_ * HD_;  // 4,194,304

  unsigned short* hb = (unsigned short*)d_ws;
  unsigned short* wqb = hb + NHID;
  unsigned short* wob = wqb + NWQ;
  unsigned short* Qb = wob + NWO;
  unsigned short* Kb = Qb + NQKV;
  unsigned short* Vtb = Kb + NQKV;
  unsigned short* attn = Vtb + NQKV;
  int* lens = (int*)(attn + NQKV);

  prep<<<dim3(4096 + B_), dim3(256), 0, stream>>>(hidden, w_qkv, w_out, amask,
                                                  hb, lens);
  qkv_gemm<<<dim3(1536), dim3(256), 0, stream>>>(hb, wqb, pos_xyz, Qb, Kb,
                                                 Vtb);
  flash_mfma<<<dim3(S_ / 64, B_ * NH_), dim3(256), 0, stream>>>(
      Qb, Kb, Vtb, lens, attn);
  out_gemm<<<dim3(16, 64), dim3(256), 0, stream>>>(attn, wob, out);
}

// Round 15
// 209.561 us; speedup vs baseline: 1.0335x; 1.0015x over previous
//
#include <hip/hip_runtime.h>
#include <math.h>

extern "C" __device__ float __ocml_native_exp2_f32(float);

namespace {

typedef __attribute__((ext_vector_type(8))) short short8;   // 8 bf16 = 4 VGPRs
typedef __attribute__((ext_vector_type(4))) short short4b;  // 4 bf16 = 8B store
typedef __attribute__((ext_vector_type(4))) float floatx4;  // MFMA C/D frag

constexpr int B_ = 2;
constexpr int S_ = 2048;
constexpr int DM_ = 1024;
constexpr int NH_ = 16;
constexpr int HD_ = 64;

// fp32 -> bf16 round-to-nearest-even
__device__ inline unsigned short f2bf(float f) {
  unsigned u = __builtin_bit_cast(unsigned, f);
  u += 0x7fffu + ((u >> 16) & 1u);
  return (unsigned short)(u >> 16);
}

// DPP row-rotate (within 16-lane rows) — reduction butterflies without LDS.
template <int CTRL>
__device__ inline float dpp_ror(float x) {
  const int r = __builtin_amdgcn_update_dpp(
      0, __builtin_bit_cast(int, x), CTRL, 0xF, 0xF, false);
  return __builtin_bit_cast(float, r);
}

// async global->LDS, 16B per lane; lds dest must be wave-uniform (lane i lands
// at lds + i*16).
__device__ inline void gl2lds16(const unsigned short* g, unsigned short* l) {
  __builtin_amdgcn_global_load_lds(
      (const __attribute__((address_space(1))) unsigned int*)g,
      (__attribute__((address_space(3))) unsigned int*)l, 16, 0, 0);
}

// ---------------------------------------------------------------------------
// Fused prep: one launch does all three f32->bf16 conversions (dsts are
// contiguous in workspace: hb | wqb | wob) + the 2 length reductions.
// ---------------------------------------------------------------------------
__global__ __launch_bounds__(256) void prep(
    const float* __restrict__ hidden, const float* __restrict__ wqkv,
    const float* __restrict__ wout, const unsigned char* __restrict__ mask,
    unsigned short* __restrict__ hb, int* __restrict__ lengths) {
  const int bid = blockIdx.x;
  if (bid < 4096) {
    const int i = bid * 256 + threadIdx.x;  // short8 index into combined dst
    const float* src;
    int off;
    if (i < 524288)              { src = hidden; off = 0; }
    else if (i < 524288 + 393216){ src = wqkv;   off = 524288; }
    else                         { src = wout;   off = 524288 + 393216; }
    const size_t j = (size_t)(i - off);
    const float4 a = ((const float4*)src)[j * 2];
    const float4 b = ((const float4*)src)[j * 2 + 1];
    short8 v;
    v[0] = (short)f2bf(a.x); v[1] = (short)f2bf(a.y);
    v[2] = (short)f2bf(a.z); v[3] = (short)f2bf(a.w);
    v[4] = (short)f2bf(b.x); v[5] = (short)f2bf(b.y);
    v[6] = (short)f2bf(b.z); v[7] = (short)f2bf(b.w);
    ((short8*)hb)[i] = v;
  } else {
    const int b = bid - 4096;
    const int es1 = (mask[1] != 0);  // byte-1 nonzero => 1-byte bool storage
    __shared__ int cnt;
    if (threadIdx.x == 0) cnt = 0;
    __syncthreads();
    int local = 0;
    for (int s = threadIdx.x; s < S_; s += blockDim.x) {
      bool nz;
      if (es1) nz = mask[b * S_ + s] != 0;
      else     nz = ((const unsigned int*)mask)[b * S_ + s] != 0;
      local += nz ? 1 : 0;
    }
    atomicAdd(&cnt, local);
    __syncthreads();
    if (threadIdx.x == 0) lengths[b] = cnt;
  }
}

// ---------------------------------------------------------------------------
// QKV GEMM (bf16 MFMA): C[m][n] = sum_k A[m][k] * W[n][k]
// M=4096, N=3072, K=1024. 128x64 tiles -> 1536 blocks = 6/CU resident.
// BK=64 as two BK=32 half-tiles. 4 waves each 64x32. XCD-chunked map.
// NEW (isolated this round): chunk-XOR LDS swizzle on the 64B-stride tiles —
// LDS[row][p] = Global[row][p ^ ((row>>1)&3)], applied on the pre-swizzled
// GLOBAL source (gl2lds writes linearly; row bases are multiples of 16 so
// sel = (r_in>>1)&3 = (lane>>3)&3) and on the ds_read chunk
// (q4 ^ ((lm>>1)&3)). Spreads the fragment reads over all 32 banks at
// 2 lanes/bank -> kills the 8-way conflict (4.7M cycles in r14).
// Coalesced epilogues; q pre-scaled by 1/8*log2(e) for base-2 softmax.
// ---------------------------------------------------------------------------
__global__ __launch_bounds__(256) void qkv_gemm(
    const unsigned short* __restrict__ A, const unsigned short* __restrict__ W,
    const int* __restrict__ pos_xyz,
    unsigned short* __restrict__ Qb, unsigned short* __restrict__ Kb,
    unsigned short* __restrict__ Vtb) {
  __shared__ __align__(16) unsigned short As[2][128 * 32];
  __shared__ __align__(16) unsigned short Bs[2][64 * 32];
  // lin -> (xcd, t); xcd owns m-groups [ (xcd>>1)*8, +8 ) x n-groups
  // [ (xcd&1)*24, +24 ). Bijective since 1536 % 8 == 0.
  const int lin = blockIdx.x;                           // 0..1535
  const int xcd = lin & 7, t = lin >> 3;                // t 0..191
  const int m0 = ((xcd >> 1) * 8 + t / 24) * 128;       // 0..3968
  const int n0 = ((xcd & 1) * 24 + t % 24) * 64;        // 0..3008
  const int w = threadIdx.x >> 6, lane = threadIdx.x & 63;
  const int lm = lane & 15, q4 = lane >> 4;
  const int srowA = w * 32;                 // wave stages 32 rows of A
  const int srowB = w * 16;                 // and 16 rows of B
  const int r_in = lane >> 2;
  const int c_sw = (((lane & 3) ^ ((lane >> 3) & 3)) << 3);  // swizzled src
  const int rsw = (lm >> 1) & 3;            // read-side swizzle sel
  const int wr = (w >> 1) * 64, wc = (w & 1) * 32;
  const int which = n0 >> 10;               // 0=Q 1=K 2=V (block-uniform)
  // acc: which==2 -> [mt(4)][nt(2)] at acc[mt*2+nt]; else [nt(2)][mt(4)]
  // at acc[nt*4+mt].
  floatx4 acc[8];
  const floatx4 z4 = {0.f, 0.f, 0.f, 0.f};
#pragma unroll
  for (int i = 0; i < 8; i++) acc[i] = z4;

  const unsigned short* gA0 = A + (size_t)(m0 + srowA + r_in) * DM_ + c_sw;
  const unsigned short* gA1 = A + (size_t)(m0 + srowA + 16 + r_in) * DM_ + c_sw;
  const unsigned short* gB0 = W + (size_t)(n0 + srowB + r_in) * DM_ + c_sw;

  for (int k0 = 0; k0 < DM_; k0 += 64) {
#pragma unroll
    for (int hh = 0; hh < 2; hh++) {
      const int ko = k0 + hh * 32;
      gl2lds16(gA0 + ko, As[hh] + srowA * 32);
      gl2lds16(gA1 + ko, As[hh] + (srowA + 16) * 32);
      gl2lds16(gB0 + ko, Bs[hh] + srowB * 32);
    }
    __syncthreads();
#pragma unroll
    for (int hh = 0; hh < 2; hh++) {
      short8 af[4], bf[2];
#pragma unroll
      for (int t2 = 0; t2 < 4; t2++)
        af[t2] = *(const short8*)(As[hh] + (wr + t2 * 16 + lm) * 32 +
                                  ((q4 ^ rsw) << 3));
#pragma unroll
      for (int t2 = 0; t2 < 2; t2++)
        bf[t2] = *(const short8*)(Bs[hh] + (wc + t2 * 16 + lm) * 32 +
                                  ((q4 ^ rsw) << 3));
      if (which == 2) {
#pragma unroll
        for (int i = 0; i < 4; i++)
#pragma unroll
          for (int j = 0; j < 2; j++)
            acc[i * 2 + j] = __builtin_amdgcn_mfma_f32_16x16x32_bf16(
                af[i], bf[j], acc[i * 2 + j], 0, 0, 0);
      } else {
#pragma unroll
        for (int i = 0; i < 2; i++)
#pragma unroll
          for (int j = 0; j < 4; j++)
            acc[i * 4 + j] = __builtin_amdgcn_mfma_f32_16x16x32_bf16(
                bf[i], af[j], acc[i * 4 + j], 0, 0, 0);
      }
    }
    __syncthreads();
  }

  const int h = (n0 & 1023) >> 6;  // block covers 64 cols = one head-block
  if (which == 2) {
#pragma unroll
    for (int nt = 0; nt < 2; nt++) {
      const int d = wc + nt * 16 + lm;
#pragma unroll
      for (int mt = 0; mt < 4; mt++) {
        const int m = m0 + wr + mt * 16 + q4 * 4;
        const int bi = m >> 11, si = m & (S_ - 1);
        short4b pk;
#pragma unroll
        for (int r = 0; r < 4; r++) pk[r] = (short)f2bf(acc[mt * 2 + nt][r]);
        *(short4b*)(Vtb + ((size_t)(bi * NH_ + h) * HD_ + d) * S_ + si) = pk;
      }
    }
  } else {
    unsigned short* Dst = (which == 0) ? Qb : Kb;
    // q pre-scaled by 1/8 * log2(e) for base-2 flash softmax
    const float osc = (which == 0) ? 0.125f * 1.44269504088896f : 1.0f;
#pragma unroll
    for (int nt = 0; nt < 2; nt++) {
      const int dbase = wc + nt * 16 + q4 * 4;  // even; both pairs in-register
      const int p0 = dbase >> 1;           // even -> p0,p0+1 share an axis
      int axis, j0, dseg;
      if (p0 < 10)      { axis = 0; j0 = p0;      dseg = 20; }
      else if (p0 < 20) { axis = 1; j0 = p0 - 10; dseg = 20; }
      else              { axis = 2; j0 = p0 - 20; dseg = 24; }
      // 10000^(-2j/dseg) = exp(-2j/dseg * ln 1e4)
      const float invf0 =
          __expf(-(2.0f * (float)j0 / (float)dseg) * 9.210340371976184f);
      const float invf1 =
          __expf(-(2.0f * (float)(j0 + 1) / (float)dseg) * 9.210340371976184f);
#pragma unroll
      for (int mt = 0; mt < 4; mt++) {
        const int m = m0 + wr + mt * 16 + lm;
        const int bi = m >> 11, si = m & (S_ - 1);
        const int pos = pos_xyz[((size_t)bi * S_ + si) * 3 + axis];
        short4b pk;
#pragma unroll
        for (int u = 0; u < 2; u++) {
          const float ve = acc[nt * 4 + mt][2 * u];
          const float vo = acc[nt * 4 + mt][2 * u + 1];
          float sn, cs;
          sincosf((float)pos * (u ? invf1 : invf0), &sn, &cs);
          pk[2 * u]     = (short)f2bf(fmaf(ve, cs, -vo * sn) * osc);
          pk[2 * u + 1] = (short)f2bf(fmaf(vo, cs, ve * sn) * osc);
        }
        *(short4b*)(Dst + ((size_t)(bi * NH_ + h) * S_ + si) * HD_ + dbase) = pk;
      }
    }
  }
}

// ---------------------------------------------------------------------------
// Flash attention on MFMA (round-12 version, verified: common-path tile has
// zero cross-lane reductions; defer check on per-lane max; l as per-lane
// partial reduced once after the k-loop).
// ---------------------------------------------------------------------------
__global__ __launch_bounds__(256) void flash_mfma(
    const unsigned short* __restrict__ Q, const unsigned short* __restrict__ Kg,
    const unsigned short* __restrict__ Vt, const int* __restrict__ lengths,
    unsigned short* __restrict__ Oa) {
  __shared__ __align__(16) unsigned short Ks[2 * 64 * 64];
  __shared__ __align__(16) unsigned short Vs[2 * 64 * 64];
  __shared__ __align__(16) unsigned short Ps[4][16 * 64];

  const int lin = blockIdx.y * gridDim.x + blockIdx.x;  // 0..1023
  const int xcd = lin & 7, k = lin >> 3;                // k 0..127 within XCD
  const int s = k >> 5, c = k & 31;
  const int pc = (c & 1) ? 31 - (c >> 1) : (c >> 1);    // pair permutation
  const int qt = (s & 1) ? 31 - pc : pc;
  const int bh = xcd * 4 + s;                           // 4 bh per XCD (L2)
  const int b = bh >> 4, h = bh & 15;
  const int q0 = qt * 64;

  const int w = threadIdx.x >> 6, lane = threadIdx.x & 63;
  const int lm = lane & 15, q4 = lane >> 4;
  const int len = lengths[b];
  const unsigned short* Qp = Q + (size_t)bh * S_ * HD_;
  const unsigned short* Kp = Kg + (size_t)bh * S_ * HD_;
  const unsigned short* Vp = Vt + (size_t)bh * HD_ * S_;

  const int r8 = lane >> 3, c8 = lane & 7;
  const int rs0 = w * 16 + r8, rs1 = rs0 + 8;           // (rs1&7) == (rs0&7)
  const int cs = (c8 ^ (rs0 & 7)) << 3;                 // chunk -> shorts
  const unsigned short* gK0 = Kp + (size_t)rs0 * HD_ + cs;
  const unsigned short* gK1 = Kp + (size_t)rs1 * HD_ + cs;
  const unsigned short* gV0 = Vp + (size_t)rs0 * S_ + cs;
  const unsigned short* gV1 = Vp + (size_t)rs1 * S_ + cs;
  unsigned short* dK0 = Ks + w * 16 * 64;
  unsigned short* dK1 = Ks + (w * 16 + 8) * 64;
  unsigned short* dV0 = Vs + w * 16 * 64;
  unsigned short* dV1 = Vs + (w * 16 + 8) * 64;

  const int qrow = q0 + w * 16 + lm;  // A-operand row for this lane
  short8 qf[2];
  qf[0] = *(const short8*)(Qp + (size_t)qrow * HD_ + q4 * 8);
  qf[1] = *(const short8*)(Qp + (size_t)qrow * HD_ + 32 + q4 * 8);

  const floatx4 z4 = {0.f, 0.f, 0.f, 0.f};
  floatx4 o[4];
#pragma unroll
  for (int dt = 0; dt < 4; dt++) o[dt] = z4;
  float m_i[4], lp[4];  // m uniform per 16-lane group; lp per-lane partial
#pragma unroll
  for (int r = 0; r < 4; r++) { m_i[r] = -1e30f; lp[r] = 0.0f; }

  unsigned short* ps = Ps[w];
  const int ktiles = min(qt + 1, (len + 63) >> 6);

  // prologue: stage tile 0 into buffer 0
  gl2lds16(gK0, dK0);
  gl2lds16(gK1, dK1);
  gl2lds16(gV0, dV0);
  gl2lds16(gV1, dV1);
  __syncthreads();

  int cur = 0;
  for (int kt = 0; kt < ktiles; kt++) {
    const int k0 = kt * 64;
    if (kt + 1 < ktiles) {
      const size_t koff = (size_t)(k0 + 64) * HD_;
      const int nb = (cur ^ 1) * 4096;
      gl2lds16(gK0 + koff, dK0 + nb);
      gl2lds16(gK1 + koff, dK1 + nb);
      gl2lds16(gV0 + (k0 + 64), dV0 + nb);
      gl2lds16(gV1 + (k0 + 64), dV1 + nb);
    }
    const unsigned short* kc = Ks + cur * 4096;
    const unsigned short* vc = Vs + cur * 4096;

    // S = Q K^T  (64 cols in 4 n-tiles); K frags from swizzled LDS.
    floatx4 sc[4];
    __builtin_amdgcn_s_setprio(1);
#pragma unroll
    for (int nt = 0; nt < 4; nt++) {
      const int row = nt * 16 + lm, sw = row & 7;
      const unsigned short* kb = kc + row * 64;
      const short8 b0 = *(const short8*)(kb + ((q4 ^ sw) << 3));
      const short8 b1 = *(const short8*)(kb + (((q4 + 4) ^ sw) << 3));
      sc[nt] = __builtin_amdgcn_mfma_f32_16x16x32_bf16(qf[0], b0, z4, 0, 0, 0);
      sc[nt] = __builtin_amdgcn_mfma_f32_16x16x32_bf16(qf[1], b1, sc[nt], 0, 0, 0);
    }
    __builtin_amdgcn_s_setprio(0);
    // mask only where it can trigger: diagonal tile or len-tail tile
    if (kt == qt || k0 + 64 > len) {
#pragma unroll
      for (int nt = 0; nt < 4; nt++) {
        const int col = k0 + nt * 16 + lm;
#pragma unroll
        for (int r = 0; r < 4; r++) {
          const int row = q0 + w * 16 + q4 * 4 + r;
          if (col > row || col >= len) sc[nt][r] = -1e30f;
        }
      }
    }
    // online softmax, base-2. Common path: no cross-lane ops at all.
    float lmax[4];
#pragma unroll
    for (int r = 0; r < 4; r++)
      lmax[r] = fmaxf(fmaxf(sc[0][r], sc[1][r]), fmaxf(sc[2][r], sc[3][r]));
    const bool ok = (lmax[0] <= m_i[0] + 8.f) && (lmax[1] <= m_i[1] + 8.f) &&
                    (lmax[2] <= m_i[2] + 8.f) && (lmax[3] <= m_i[3] + 8.f);
    if (!__all(ok)) {
      // rare: full DPP row-max, update m (stays group-uniform), rescale o,lp
#pragma unroll
      for (int r = 0; r < 4; r++) {
        float mx = lmax[r];
        mx = fmaxf(mx, dpp_ror<0x121>(mx));
        mx = fmaxf(mx, dpp_ror<0x122>(mx));
        mx = fmaxf(mx, dpp_ror<0x124>(mx));
        mx = fmaxf(mx, dpp_ror<0x128>(mx));
        const float mt = fmaxf(m_i[r], mx);
        const float al = __ocml_native_exp2_f32(m_i[r] - mt);
        lp[r] *= al;
        m_i[r] = mt;
#pragma unroll
        for (int dt = 0; dt < 4; dt++) o[dt][r] *= al;
      }
    }
#pragma unroll
    for (int r = 0; r < 4; r++) {
      float rs = 0.0f;
#pragma unroll
      for (int nt = 0; nt < 4; nt++) {
        const float pp = __ocml_native_exp2_f32(sc[nt][r] - m_i[r]);
        sc[nt][r] = pp;
        rs += pp;
      }
      lp[r] += rs;  // per-lane partial; reduced once after the loop
    }
    // P: D-layout -> bf16 -> wave-private LDS strip, stride 64 + chunk-XOR
#pragma unroll
    for (int nt = 0; nt < 4; nt++)
#pragma unroll
      for (int r = 0; r < 4; r++) {
        const int row = q4 * 4 + r;
        const int cc = (((nt * 2 + (lm >> 3)) ^ (row & 7)) << 3) | (lm & 7);
        ps[row * 64 + cc] = f2bf(sc[nt][r]);
      }
    // O += P V   (V^T rows are d; V frags from swizzled LDS)
    __builtin_amdgcn_s_setprio(1);
#pragma unroll
    for (int ks = 0; ks < 2; ks++) {
      const short8 pf = *(const short8*)(
          ps + lm * 64 + ((((ks << 2) + q4) ^ (lm & 7)) << 3));
#pragma unroll
      for (int dt = 0; dt < 4; dt++) {
        const int row = dt * 16 + lm, sw = row & 7;
        const short8 vf = *(const short8*)(
            vc + row * 64 + ((((ks << 2) + q4) ^ sw) << 3));
        o[dt] = __builtin_amdgcn_mfma_f32_16x16x32_bf16(pf, vf, o[dt], 0, 0, 0);
      }
    }
    __builtin_amdgcn_s_setprio(0);
    __syncthreads();  // drains next-tile staging; all waves done reading cur
    cur ^= 1;
  }
  // one DPP sum-ladder per row to finish l, then normalize + write attn
  float invl[4];
#pragma unroll
  for (int r = 0; r < 4; r++) {
    float l = lp[r];
    l += dpp_ror<0x121>(l);
    l += dpp_ror<0x122>(l);
    l += dpp_ror<0x124>(l);
    l += dpp_ror<0x128>(l);
    invl[r] = 1.0f / l;
  }
#pragma unroll
  for (int dt = 0; dt < 4; dt++)
#pragma unroll
    for (int r = 0; r < 4; r++) {
      const int row = q0 + w * 16 + q4 * 4 + r;
      const int col = h * HD_ + dt * 16 + lm;
      Oa[((size_t)b * S_ + row) * DM_ + col] = f2bf(o[dt][r] * invl[r]);
    }
}

// ---------------------------------------------------------------------------
// Out projection (bf16 MFMA): C[m][n] = sum_k A[m][k] * W[n][k], fp32 out.
// M=4096, N=1024, K=1024. 64x64 tiles, 1024 blocks (4/CU), XCD-grouped.
// BK=64 as two BK=32 half-tiles (r14). NEW: same chunk-XOR LDS swizzle as
// qkv_gemm (pre-swizzled global source + swizzled ds_read chunk).
// Swapped operands -> one float4 (16B) store per (nt,mt).
// ---------------------------------------------------------------------------
__global__ __launch_bounds__(256) void out_gemm(
    const unsigned short* __restrict__ A, const unsigned short* __restrict__ W,
    float* __restrict__ C) {
  __shared__ __align__(16) unsigned short As[2][64 * 32];
  __shared__ __align__(16) unsigned short Bs[2][64 * 32];
  const int lin = blockIdx.y * gridDim.x + blockIdx.x;  // 0..1023
  const int xcd = lin & 7, t = lin >> 3;                // t 0..127
  const int m0 = (xcd * 8 + (t >> 4)) * 64;             // 0..4095
  const int n0 = (t & 15) * 64;                         // 0..1023
  const int w = threadIdx.x >> 6, lane = threadIdx.x & 63;
  const int lm = lane & 15, q4 = lane >> 4;
  const int srow = w * 16;                  // wave stages 16 rows of A and B
  const int r_in = lane >> 2;
  const int c_sw = (((lane & 3) ^ ((lane >> 3) & 3)) << 3);  // swizzled src
  const int rsw = (lm >> 1) & 3;            // read-side swizzle sel
  const int wr = (w >> 1) * 32, wc = (w & 1) * 32;
  floatx4 acc[2][2];  // acc[nt][mt]: row <-> n, col <-> m
  const floatx4 z4 = {0.f, 0.f, 0.f, 0.f};
#pragma unroll
  for (int i = 0; i < 2; i++)
#pragma unroll
    for (int j = 0; j < 2; j++) acc[i][j] = z4;

  const unsigned short* gA0 = A + (size_t)(m0 + srow + r_in) * DM_ + c_sw;
  const unsigned short* gB0 = W + (size_t)(n0 + srow + r_in) * DM_ + c_sw;

  for (int k0 = 0; k0 < DM_; k0 += 64) {
#pragma unroll
    for (int hh = 0; hh < 2; hh++) {
      const int ko = k0 + hh * 32;
      gl2lds16(gA0 + ko, As[hh] + srow * 32);
      gl2lds16(gB0 + ko, Bs[hh] + srow * 32);
    }
    __syncthreads();
#pragma unroll
    for (int hh = 0; hh < 2; hh++) {
      short8 af[2], bf[2];
#pragma unroll
      for (int t2 = 0; t2 < 2; t2++)
        af[t2] = *(const short8*)(As[hh] + (wr + t2 * 16 + lm) * 32 +
                                  ((q4 ^ rsw) << 3));
#pragma unroll
      for (int t2 = 0; t2 < 2; t2++)
        bf[t2] = *(const short8*)(Bs[hh] + (wc + t2 * 16 + lm) * 32 +
                                  ((q4 ^ rsw) << 3));
#pragma unroll
      for (int i = 0; i < 2; i++)
#pragma unroll
        for (int j = 0; j < 2; j++)
          acc[i][j] = __builtin_amdgcn_mfma_f32_16x16x32_bf16(
              bf[i], af[j], acc[i][j], 0, 0, 0);
    }
    __syncthreads();
  }
#pragma unroll
  for (int nt = 0; nt < 2; nt++) {
    const int nbase = n0 + wc + nt * 16 + q4 * 4;
#pragma unroll
    for (int mt = 0; mt < 2; mt++) {
      const int m = m0 + wr + mt * 16 + lm;
      *(floatx4*)(C + (size_t)m * DM_ + nbase) = acc[nt][mt];
    }
  }
}

}  // namespace

extern "C" void kernel_launch(void* const* d_in, const int* in_sizes, int n_in,
                              void* d_out, int out_size, void* d_ws, size_t ws_size,
                              hipStream_t stream) {
  const float* hidden = (const float*)d_in[0];          // (2,2048,1024) f32
  const float* w_qkv = (const float*)d_in[1];           // (3072,1024) f32
  const float* w_out = (const float*)d_in[2];           // (1024,1024) f32
  const unsigned char* amask = (const unsigned char*)d_in[3];  // (2,2048) bool
  const int* pos_xyz = (const int*)d_in[5];             // (2,2048,3) i32
  float* out = (float*)d_out;                           // (2,2048,1024) f32

  constexpr size_t NHID = (size_t)B_ * S_ * DM_;        // 4,194,304
  constexpr size_t NWQ = (size_t)3 * DM_ * DM_;         // 3,145,728
  constexpr size_t NWO = (size_t)DM_ * DM_;             // 1,048,576
  constexpr size_t NQKV = (size_t)B_ * NH_ * S_ * HD_;  // 4,194,304

  unsigned short* hb = (unsigned short*)d_ws;
  unsigned short* wqb = hb + NHID;
  unsigned short* wob = wqb + NWQ;
  unsigned short* Qb = wob + NWO;
  unsigned short* Kb = Qb + NQKV;
  unsigned short* Vtb = Kb + NQKV;
  unsigned short* attn = Vtb + NQKV;
  int* lens = (int*)(attn + NQKV);

  prep<<<dim3(4096 + B_), dim3(256), 0, stream>>>(hidden, w_qkv, w_out, amask,
                                                  hb, lens);
  qkv_gemm<<<dim3(1536), dim3(256), 0, stream>>>(hb, wqb, pos_xyz, Qb, Kb,
                                                 Vtb);
  flash_mfma<<<dim3(S_ / 64, B_ * NH_), dim3(256), 0, stream>>>(
      Qb, Kb, Vtb, lens, attn);
  out_gemm<<<dim3(16, 64), dim3(256), 0, stream>>>(attn, wob, out);
}